// Round 1
// baseline (1956.658 us; speedup 1.0000x reference)
//
#include <hip/hip_runtime.h>
#include <hip/hip_bf16.h>

#define NEG_SLOPE 0.01f

__device__ __forceinline__ void atomAddF(float* p, float v) {
    unsafeAtomicAdd(p, v);   // HW global_atomic_add_f32 (avoids CAS fallback)
}

// ---- degree: deg[row[e]] += attr[e] -------------------------------------
__global__ void deg_kernel(const int* __restrict__ row, const float* __restrict__ attr,
                           float* __restrict__ deg, int E) {
    int i = blockIdx.x * blockDim.x + threadIdx.x;
    if (i < E) atomAddF(&deg[row[i]], attr[i]);
}

// ---- dinv in-place: deg -> deg>0 ? rsqrt(deg) : 0 -----------------------
__global__ void dinv_kernel(float* deg, int N) {
    int i = blockIdx.x * blockDim.x + threadIdx.x;
    if (i < N) {
        float d = deg[i];
        deg[i] = d > 0.f ? rsqrtf(d) : 0.f;
    }
}

// ---- norm[e] = -dinv[row]*attr*dinv[col] --------------------------------
__global__ void norm_kernel(const int* __restrict__ row, const int* __restrict__ col,
                            const float* __restrict__ attr, const float* __restrict__ dinv,
                            float* __restrict__ norm, int E) {
    int i = blockIdx.x * blockDim.x + threadIdx.x;
    if (i < E) norm[i] = -dinv[row[i]] * attr[i] * dinv[col[i]];
}

// ---- h1 = leaky_relu(x @ w1 + b1), x:(N,20) w:(20,32) -------------------
__global__ void h1_kernel(const float* __restrict__ x, const float* __restrict__ w,
                          const float* __restrict__ b, float* __restrict__ h1, int N) {
    __shared__ float ws[20 * 32];
    __shared__ float bs[32];
    for (int t = threadIdx.x; t < 640; t += blockDim.x) ws[t] = w[t];
    if (threadIdx.x < 32) bs[threadIdx.x] = b[threadIdx.x];
    __syncthreads();
    int i = blockIdx.x * blockDim.x + threadIdx.x;
    if (i >= N) return;
    float xi[20];
#pragma unroll
    for (int k = 0; k < 20; k++) xi[k] = x[i * 20 + k];
    float acc[32];
#pragma unroll
    for (int j = 0; j < 32; j++) acc[j] = bs[j];
#pragma unroll
    for (int k = 0; k < 20; k++) {
        float a = xi[k];
#pragma unroll
        for (int j = 0; j < 32; j++) acc[j] += a * ws[k * 32 + j];
    }
#pragma unroll
    for (int j = 0; j < 32; j++) {
        float v = acc[j];
        h1[(long)i * 32 + j] = v > 0.f ? v : v * NEG_SLOPE;
    }
}

// ---- p1[row[e]] += norm[e] * h1[col[e]]  (8 threads/edge, float4 each) --
__global__ void prop1_kernel(const int* __restrict__ row, const int* __restrict__ col,
                             const float* __restrict__ norm, const float* __restrict__ h1,
                             float* __restrict__ p1, int E) {
    long idx = (long)blockIdx.x * blockDim.x + threadIdx.x;
    long e = idx >> 3;
    int part = (int)(idx & 7);
    if (e >= E) return;
    int r = row[e], c = col[e];
    float nm = norm[e];
    float4 v = ((const float4*)(h1 + (long)c * 32))[part];
    float* dst = p1 + (long)r * 32 + part * 4;
    atomAddF(dst + 0, nm * v.x);
    atomAddF(dst + 1, nm * v.y);
    atomAddF(dst + 2, nm * v.z);
    atomAddF(dst + 3, nm * v.w);
}

// ---- h2 = leaky_relu(h1 @ w2_0 + p1 @ w2_1 + b2), 32 -> 64 --------------
__global__ void h2_kernel(const float* __restrict__ h1, const float* __restrict__ p1,
                          const float* __restrict__ w0, const float* __restrict__ w1,
                          const float* __restrict__ b, float* __restrict__ h2, int N) {
    __shared__ float w0s[32 * 64];
    __shared__ float w1s[32 * 64];
    __shared__ float bs[64];
    for (int t = threadIdx.x; t < 2048; t += blockDim.x) { w0s[t] = w0[t]; w1s[t] = w1[t]; }
    if (threadIdx.x < 64) bs[threadIdx.x] = b[threadIdx.x];
    __syncthreads();
    int i = blockIdx.x * blockDim.x + threadIdx.x;
    if (i >= N) return;
    float acc[64];
#pragma unroll
    for (int j = 0; j < 64; j++) acc[j] = bs[j];
    const float4* h1v = (const float4*)(h1 + (long)i * 32);
    const float4* p1v = (const float4*)(p1 + (long)i * 32);
#pragma unroll
    for (int k4 = 0; k4 < 8; k4++) {
        float4 a = h1v[k4];
        float4 p = p1v[k4];
        float av[4] = {a.x, a.y, a.z, a.w};
        float pv[4] = {p.x, p.y, p.z, p.w};
#pragma unroll
        for (int s = 0; s < 4; s++) {
            int k = k4 * 4 + s;
#pragma unroll
            for (int j = 0; j < 64; j++) acc[j] += av[s] * w0s[k * 64 + j] + pv[s] * w1s[k * 64 + j];
        }
    }
#pragma unroll
    for (int j = 0; j < 64; j++) {
        float v = acc[j];
        acc[j] = v > 0.f ? v : v * NEG_SLOPE;
    }
    float4* out = (float4*)(h2 + (long)i * 64);
#pragma unroll
    for (int j = 0; j < 16; j++)
        out[j] = make_float4(acc[4 * j], acc[4 * j + 1], acc[4 * j + 2], acc[4 * j + 3]);
}

// ---- s1[j] = sum_i h2[i][j] ---------------------------------------------
__global__ void sum_h2_kernel(const float* __restrict__ h2, float* __restrict__ s1, long total) {
    long tid = (long)blockIdx.x * blockDim.x + threadIdx.x;
    long stride = (long)gridDim.x * blockDim.x;   // multiple of 64
    float acc = 0.f;
    for (long idx = tid; idx < total; idx += stride) acc += h2[idx];
    __shared__ float red[256];
    red[threadIdx.x] = acc;
    __syncthreads();
    if (threadIdx.x < 64) {
        float s = red[threadIdx.x] + red[threadIdx.x + 64] + red[threadIdx.x + 128] + red[threadIdx.x + 192];
        atomAddF(&s1[threadIdx.x], s);   // feature id == threadIdx.x (stride mult of 64)
    }
}

// ---- s2[j] = sum_e norm[e] * h2[col[e]][j]  (16 threads/edge) -----------
__global__ void edge_sum_kernel(const int* __restrict__ col, const float* __restrict__ norm,
                                const float* __restrict__ h2, float* __restrict__ s2, long E) {
    long tid = (long)blockIdx.x * blockDim.x + threadIdx.x;
    long stride = (long)gridDim.x * blockDim.x;   // multiple of 16
    int part = (int)(tid & 15);
    float4 acc = make_float4(0.f, 0.f, 0.f, 0.f);
    long total = E * 16;
    for (long idx = tid; idx < total; idx += stride) {
        long e = idx >> 4;
        float nm = norm[e];
        int c = col[e];
        float4 v = ((const float4*)(h2 + (long)c * 64))[part];
        acc.x += nm * v.x; acc.y += nm * v.y; acc.z += nm * v.z; acc.w += nm * v.w;
    }
    __shared__ float red[64];
    if (threadIdx.x < 64) red[threadIdx.x] = 0.f;
    __syncthreads();
    atomicAdd(&red[part * 4 + 0], acc.x);
    atomicAdd(&red[part * 4 + 1], acc.y);
    atomicAdd(&red[part * 4 + 2], acc.z);
    atomicAdd(&red[part * 4 + 3], acc.w);
    __syncthreads();
    if (threadIdx.x < 64) atomAddF(&s2[threadIdx.x], red[threadIdx.x]);
}

// ---- pooled = (s1/N)@w30 + (s2/N)@w31 + b3; out = log_softmax -----------
__global__ void final_kernel(const float* __restrict__ s1, const float* __restrict__ s2,
                             const float* __restrict__ w30, const float* __restrict__ w31,
                             const float* __restrict__ b3, float* __restrict__ out, float invN) {
    if (threadIdx.x != 0 || blockIdx.x != 0) return;
    float p[2];
    for (int c = 0; c < 2; c++) {
        float a = 0.f;
        for (int k = 0; k < 64; k++) a += s1[k] * w30[k * 2 + c] + s2[k] * w31[k * 2 + c];
        p[c] = a * invN + b3[c];
    }
    float m = fmaxf(p[0], p[1]);
    float lse = m + logf(expf(p[0] - m) + expf(p[1] - m));
    out[0] = p[0] - lse;
    out[1] = p[1] - lse;
}

extern "C" void kernel_launch(void* const* d_in, const int* in_sizes, int n_in,
                              void* d_out, int out_size, void* d_ws, size_t ws_size,
                              hipStream_t stream) {
    const float* x    = (const float*)d_in[0];
    const int*   ei   = (const int*)d_in[1];
    const float* attr = (const float*)d_in[2];
    const float* w1_0 = (const float*)d_in[3];
    const float* b1   = (const float*)d_in[4];
    const float* w2_0 = (const float*)d_in[5];
    const float* w2_1 = (const float*)d_in[6];
    const float* b2   = (const float*)d_in[7];
    const float* w3_0 = (const float*)d_in[8];
    const float* w3_1 = (const float*)d_in[9];
    const float* b3   = (const float*)d_in[10];

    const int N = in_sizes[0] / 20;
    const int E = in_sizes[2];
    const int* row = ei;
    const int* col = ei + E;

    float* ws = (float*)d_ws;
    float* deg  = ws;                               // N     (becomes dinv)
    float* norm = deg  + N;                         // E
    float* h1   = norm + E;                         // N*32
    float* p1   = h1   + (long)N * 32;              // N*32
    float* h2   = p1   + (long)N * 32;              // N*64
    float* s1   = h2   + (long)N * 64;              // 64
    float* s2   = s1   + 64;                        // 64

    // zero the accumulated regions (ws is poisoned before every launch)
    hipMemsetAsync(deg, 0, (size_t)N * 4, stream);
    hipMemsetAsync(p1, 0, (size_t)N * 32 * 4, stream);
    hipMemsetAsync(s1, 0, 128 * 4, stream);

    const int B = 256;
    deg_kernel<<<(E + B - 1) / B, B, 0, stream>>>(row, attr, deg, E);
    dinv_kernel<<<(N + B - 1) / B, B, 0, stream>>>(deg, N);
    norm_kernel<<<(E + B - 1) / B, B, 0, stream>>>(row, col, attr, deg, norm, E);
    h1_kernel<<<(N + B - 1) / B, B, 0, stream>>>(x, w1_0, b1, h1, N);
    {
        long t = (long)E * 8;
        prop1_kernel<<<(int)((t + B - 1) / B), B, 0, stream>>>(row, col, norm, h1, p1, E);
    }
    h2_kernel<<<(N + B - 1) / B, B, 0, stream>>>(h1, p1, w2_0, w2_1, b2, h2, N);
    sum_h2_kernel<<<256, B, 0, stream>>>(h2, s1, (long)N * 64);
    edge_sum_kernel<<<512, B, 0, stream>>>(col, norm, h2, s2, (long)E);
    final_kernel<<<1, 64, 0, stream>>>(s1, s2, w3_0, w3_1, b3, (float*)d_out, 1.0f / (float)N);
}